// Round 13
// baseline (1023.512 us; speedup 1.0000x reference)
//
#include <hip/hip_runtime.h>
#include <hip/hip_bf16.h>

typedef unsigned int u32;
typedef unsigned short u16;
typedef unsigned char u8;

typedef __attribute__((ext_vector_type(4))) float f32x4;
typedef __attribute__((ext_vector_type(8))) int i32x8;
typedef __attribute__((ext_vector_type(8))) __bf16 bf16x8;

#define NEG (-10000.0f)
#define WSCALE 16.0f
// i/f/o gates: scaleB = 0x79 (2^-6) = undo WSCALE and apply 0.25 hard-sigmoid slope in HW
// g gate:     scaleB = 0x7B (2^-4) = undo WSCALE

// ---------- helpers ----------
__device__ __forceinline__ float bf2f(u16 x){ return __uint_as_float(((u32)x) << 16); }
__device__ __forceinline__ u16 f2bf(float f){
    u32 u = __float_as_uint(f);
    u32 r = (u + 0x7fffu + ((u >> 16) & 1u)) >> 16;   // RNE
    return (u16)r;
}
__device__ __forceinline__ u32 pk_bf16(float lo, float hi){
    u32 r;
    asm volatile("v_cvt_pk_bf16_f32 %0, %1, %2" : "=v"(r) : "v"(lo), "v"(hi));
    return r;
}
// gate from pre-biased accumulator: single med3
__device__ __forceinline__ float hsig1(float a){
    return __builtin_amdgcn_fmed3f(a, 0.0f, 1.0f);
}
// softsign-rsq tanh: 3 inst
__device__ __forceinline__ float ptanh(float x){
    return x * __builtin_amdgcn_rsqf(__builtin_fmaf(x, x, 1.0f));
}

// ---------- K0: W_hh f32 -> fp8 e4m3 (x16), plus W_out f32 -> fp8 (x64, [16][512]) ----------
__global__ void k0_convert(const float* __restrict__ Whh_f,
                           const float* __restrict__ Whh_b,
                           const float* __restrict__ Wout,
                           u32* __restrict__ w8, u32* __restrict__ w8o){
    int gid = blockIdx.x * blockDim.x + threadIdx.x;   // 4 elems each
    if (gid >= 131072) return;
    int idx = gid * 4;
    int dir = idx >> 18;
    int off = idx & 0x3FFFF;
    const float* W = dir ? Whh_b : Whh_f;
    int pk = __builtin_amdgcn_cvt_pk_fp8_f32(W[off] * WSCALE, W[off + 1] * WSCALE, 0, false);
    pk = __builtin_amdgcn_cvt_pk_fp8_f32(W[off + 2] * WSCALE, W[off + 3] * WSCALE, pk, true);
    w8[gid] = (u32)pk;

    if (gid < 2048){                       // W_out: [16][512] fp8, rows 12..15 = 0
        int i4 = gid * 4;
        int n = i4 >> 9, k = i4 & 511;
        float a = 0, b = 0, c = 0, d = 0;
        if (n < 12){
            const float* wr = Wout + (size_t)n * 512 + k;
            a = wr[0] * 64.0f; b = wr[1] * 64.0f; c = wr[2] * 64.0f; d = wr[3] * 64.0f;
        }
        int p = __builtin_amdgcn_cvt_pk_fp8_f32(a, b, 0, false);
        p = __builtin_amdgcn_cvt_pk_fp8_f32(c, d, p, true);
        w8o[gid] = (u32)p;
    }
}

// ---------- K1: input projection GEMM via bf16 MFMA ----------
// X layout: X[dir][m=b*256+t][hid(256)][gate(4)] u16 — a lane's 4 gates = one uint2.
// i/f/o gates stored PRE-TRANSFORMED x' = 0.25x + 0.5; g gate raw.
__global__ __launch_bounds__(256) void k1_inproj(
    const int* __restrict__ sent, const float* __restrict__ emb,
    const float* __restrict__ Wih_f, const float* __restrict__ bih_f, const float* __restrict__ bhh_f,
    const float* __restrict__ Wih_b, const float* __restrict__ bih_b, const float* __restrict__ bhh_b,
    u16* __restrict__ X){
    int dir = blockIdx.z;
    const float* W  = dir ? Wih_b : Wih_f;
    const float* b1 = dir ? bih_b : bih_f;
    const float* b2 = dir ? bhh_b : bhh_f;
    u16* Xo = X + (size_t)dir * 8388608;

    __shared__ __align__(16) u16 As[64 * 256];
    __shared__ __align__(16) u16 Bs[64 * 256];

    int tid = threadIdx.x;
    int m0 = blockIdx.x * 64, n0 = blockIdx.y * 64;

    {
        int r = tid >> 2, q = tid & 3;
        int sid = sent[m0 + r];
        const float* arow = emb + (size_t)sid * 256 + q * 64;
        const float* brow = W + (size_t)(n0 + r) * 256 + q * 64;
        #pragma unroll
        for (int g = 0; g < 8; g++){
            int col8 = q * 8 + g;
            int sc = col8 ^ (r & 7);
            float4 a0 = *(const float4*)(arow + g * 8);
            float4 a1 = *(const float4*)(arow + g * 8 + 4);
            u32 pa[4] = { pk_bf16(a0.x, a0.y), pk_bf16(a0.z, a0.w),
                          pk_bf16(a1.x, a1.y), pk_bf16(a1.z, a1.w) };
            *(uint4*)&As[r * 256 + sc * 8] = *(uint4*)pa;
            float4 v0 = *(const float4*)(brow + g * 8);
            float4 v1 = *(const float4*)(brow + g * 8 + 4);
            u32 pb[4] = { pk_bf16(v0.x, v0.y), pk_bf16(v0.z, v0.w),
                          pk_bf16(v1.x, v1.y), pk_bf16(v1.z, v1.w) };
            *(uint4*)&Bs[r * 256 + sc * 8] = *(uint4*)pb;
        }
    }
    __syncthreads();

    int w = tid >> 6, l = tid & 63, lr = l & 15, lk = l >> 4;

    f32x4 acc[4];
    #pragma unroll
    for (int nt = 0; nt < 4; nt++) acc[nt] = (f32x4){0.f, 0.f, 0.f, 0.f};

    int am = w * 16 + lr;
    #pragma unroll
    for (int ko = 0; ko < 8; ko++){
        bf16x8 a = *(const bf16x8*)&As[am * 256 + ((ko * 4 + lk) ^ (am & 7)) * 8];
        #pragma unroll
        for (int nt = 0; nt < 4; nt++){
            int bn = nt * 16 + lr;
            bf16x8 bb = *(const bf16x8*)&Bs[bn * 256 + ((ko * 4 + lk) ^ (bn & 7)) * 8];
            acc[nt] = __builtin_amdgcn_mfma_f32_16x16x32_bf16(a, bb, acc[nt], 0, 0, 0);
        }
    }

    #pragma unroll
    for (int nt = 0; nt < 4; nt++){
        int n = n0 + nt * 16 + lr;
        float bias = b1[n] + b2[n];
        int gate = n >> 8, hid = n & 255;
        int pos = hid * 4 + gate;
        bool sig = (gate != 2);
        #pragma unroll
        for (int reg = 0; reg < 4; reg++){
            int m = m0 + w * 16 + lk * 4 + reg;
            float v = acc[nt][reg] + bias;
            if (sig) v = __builtin_fmaf(0.25f, v, 0.5f);
            Xo[(size_t)m * 1024 + pos] = f2bf(v);
        }
    }
}

// ---------- K2: MX-fp8 MFMA LSTM; 1024-thread WG (16 waves, 4/SIMD), 16-hid tiles/wave ----------
#define GSCALE(g2) ((g2) == 2 ? 0x7B7B7B7B : 0x79797979)

#define K2_STEP(S, XC, XN)                                                        \
{                                                                                 \
    int tt = dir ? (255 - (S)) : (S);                                             \
    int cur = (S) & 1, nxt = cur ^ 1;                                             \
    int sn = ((S) + 1 < 256) ? (S) + 1 : (S);                                     \
    int tn = dir ? (255 - sn) : sn;                                               \
    const u8* xband = xbase + (u32)(tn * 2048);                                   \
    _Pragma("unroll")                                                             \
    for (int r2 = 0; r2 < 4; r2++)                                                \
        XN[r2] = *(const uint2*)(xband + xo[r2]);                                 \
    i32x8 af0 = *(const i32x8*)&hl[cur][lr][lk * 32];                             \
    i32x8 af1 = *(const i32x8*)&hl[cur][lr][128 + lk * 32];                       \
    f32x4 acc[4];                                                                 \
    _Pragma("unroll")                                                             \
    for (int r2 = 0; r2 < 4; r2++){                                               \
        u32 w0 = XC[r2].x, w1 = XC[r2].y;                                         \
        acc[0][r2] = __uint_as_float(w0 << 16);                                   \
        acc[1][r2] = __uint_as_float(w0 & 0xFFFF0000u);                           \
        acc[2][r2] = __uint_as_float(w1 << 16);                                   \
        acc[3][r2] = __uint_as_float(w1 & 0xFFFF0000u);                           \
    }                                                                             \
    __builtin_amdgcn_s_setprio(1);                                                \
    _Pragma("unroll")                                                             \
    for (int g2 = 0; g2 < 4; g2++){                                               \
        acc[g2] = __builtin_amdgcn_mfma_scale_f32_16x16x128_f8f6f4(               \
            af0, wf[g2][0], acc[g2], 0, 0, 0, 0x7F7F7F7F, 0, GSCALE(g2));         \
        acc[g2] = __builtin_amdgcn_mfma_scale_f32_16x16x128_f8f6f4(               \
            af1, wf[g2][1], acc[g2], 0, 0, 0, 0x7F7F7F7F, 0, GSCALE(g2));         \
    }                                                                             \
    __builtin_amdgcn_s_setprio(0);                                                \
    u8* hband = hbase + (u32)(tt * 256);                                          \
    _Pragma("unroll")                                                             \
    for (int r2 = 0; r2 < 4; r2++){                                               \
        float gi = hsig1(acc[0][r2]);                                             \
        float gf = hsig1(acc[1][r2]);                                             \
        float gg = ptanh(acc[2][r2]);                                             \
        float go = hsig1(acc[3][r2]);                                             \
        cst[r2] = gf * cst[r2] + gi * gg;                                         \
        float hh = go * ptanh(cst[r2]);                                           \
        int pk = __builtin_amdgcn_cvt_pk_fp8_f32(hh, hh, 0, false);               \
        hl[nxt][lk * 4 + r2][hid] = (u8)pk;                                       \
        *(hband + ho[r2]) = (u8)pk;                                               \
    }                                                                             \
    asm volatile("s_waitcnt lgkmcnt(0)" ::: "memory");                            \
    __builtin_amdgcn_s_barrier();                                                 \
    __builtin_amdgcn_sched_barrier(0);                                            \
}

__global__ __launch_bounds__(1024, 4) void k2_lstm(
    const u16* __restrict__ X, const u8* __restrict__ w8,
    const float* __restrict__ h0, const float* __restrict__ c0,
    u8* __restrict__ HS8){

    int wg = blockIdx.x;
    int dir = wg >> 1, half = wg & 1;
    int tid = threadIdx.x;
    int w = tid >> 6, l = tid & 63;       // 16 waves
    int lr = l & 15, lk = l >> 4;
    int bbase = half * 16;

    __shared__ __align__(16) u8 hl[2][16][272];

    const u8* Wd = w8 + (size_t)dir * 262144;

    int hid = w * 16 + lr;                // one hidden per lane

    // --- weight fragments (loop-invariant, 64 VGPRs/wave) ---
    i32x8 wf[4][2];
    #pragma unroll
    for (int g = 0; g < 4; g++)
        #pragma unroll
        for (int ko = 0; ko < 2; ko++)
            wf[g][ko] = *(const i32x8*)(Wd + (size_t)(g * 256 + hid) * 256
                                        + ko * 128 + lk * 32);

    // --- c state: 4 batches per lane ---
    float cst[4];
    #pragma unroll
    for (int r = 0; r < 4; r++)
        cst[r] = c0[(size_t)(dir * 32 + bbase + lk * 4 + r) * 256 + hid];

    // --- uniform bases (SGPR) + loop-invariant lane byte offsets (VGPR) ---
    const u8* xbase = (const u8*)(X + (size_t)dir * 8388608);
    u8* hbase = HS8 + (size_t)dir * 2097152;
    u32 xo[4], ho[4];
    #pragma unroll
    for (int r = 0; r < 4; r++){
        xo[r] = (u32)((bbase + lk * 4 + r) * 524288 + hid * 8);
        ho[r] = (u32)((bbase + lk * 4 + r) * 65536 + hid);
    }

    // --- stage h0 (f32 -> fp8) into hl[0]: 16 rows x 256 cols, 4 bytes/thread ---
    {
        int row = tid >> 6;               // 0..15
        int col = (tid & 63) * 4;         // 0..252
        const float* src = h0 + (size_t)(dir * 32 + bbase + row) * 256 + col;
        int p0 = __builtin_amdgcn_cvt_pk_fp8_f32(src[0], src[1], 0, false);
        p0 = __builtin_amdgcn_cvt_pk_fp8_f32(src[2], src[3], p0, true);
        *(u32*)&hl[0][row][col] = (u32)p0;
    }
    __syncthreads();

    // --- prologue: X for s=0 ---
    uint2 xpA[4], xpB[4];
    {
        int tt0 = dir ? 255 : 0;
        const u8* xband = xbase + (u32)(tt0 * 2048);
        #pragma unroll
        for (int r = 0; r < 4; r++)
            xpA[r] = *(const uint2*)(xband + xo[r]);
    }

    for (int s2 = 0; s2 < 256; s2 += 2){
        K2_STEP(s2,     xpA, xpB);
        K2_STEP(s2 + 1, xpB, xpA);
    }
}

// ---------- K3: feats via fp8 MFMA: rows=(b,t), N=16 (12 used), K=512 ----------
__global__ __launch_bounds__(256) void k3_feats(
    const u8* __restrict__ HS8, const u8* __restrict__ W8o,
    const float* __restrict__ bout, float* __restrict__ feats){
    int tid = threadIdx.x;
    int wv = tid >> 6, l = tid & 63, lr = l & 15, lk = l >> 4;
    int tile = blockIdx.x * 4 + wv;          // 0..511
    int b = tile >> 4, t0 = (tile & 15) * 16;

    const u8* hf = HS8 + (size_t)b * 65536 + (t0 + lr) * 256;
    const u8* hb = HS8 + (size_t)(32 + b) * 65536 + (t0 + lr) * 256;
    const u8* wo = W8o + lr * 512;

    f32x4 acc = (f32x4){0.f, 0.f, 0.f, 0.f};
    #pragma unroll
    for (int ko = 0; ko < 8; ko++){
        long a = *(const long*)(hf + ko * 32 + lk * 8);
        long bb = *(const long*)(wo + ko * 32 + lk * 8);
        acc = __builtin_amdgcn_mfma_f32_16x16x32_fp8_fp8(a, bb, acc, 0, 0, 0);
    }
    #pragma unroll
    for (int ko = 0; ko < 8; ko++){
        long a = *(const long*)(hb + ko * 32 + lk * 8);
        long bb = *(const long*)(wo + 256 + ko * 32 + lk * 8);
        acc = __builtin_amdgcn_mfma_f32_16x16x32_fp8_fp8(a, bb, acc, 0, 0, 0);
    }

    if (lr < 12){
        float bias = bout[lr];
        #pragma unroll
        for (int reg = 0; reg < 4; reg++){
            int t = t0 + lk * 4 + reg;
            feats[((size_t)b * 256 + t) * 12 + lr] = acc[reg] * 0.015625f + bias;
        }
    }
}

// ---------- K4: CRF forward + gold, ONE WAVE per batch, barrier-free ----------
__global__ __launch_bounds__(64) void k4_crf(
    const float* __restrict__ feats, const float* __restrict__ trans,
    const int* __restrict__ tags, float* __restrict__ scores){
    int b = blockIdx.x;
    int l = threadIdx.x;
    int i = l >> 2, q = l & 3;
    bool act = (i < 12);
    int j0 = q * 3;
    float tj0 = act ? trans[i * 12 + j0 + 0] : NEG;
    float tj1 = act ? trans[i * 12 + j0 + 1] : NEG;
    float tj2 = act ? trans[i * 12 + j0 + 2] : NEG;
    float fv0 = (j0 == 0) ? 0.0f : NEG;     // START = tag 0
    float fv1 = NEG, fv2 = NEG;
    const float* fb = feats + (size_t)b * 3072;
    float fcur = act ? fb[i] : 0.0f;

    for (int t = 0; t < 256; t++){
        float e0, e1, e2;
        if (act){ e0 = fv0 + tj0; e1 = fv1 + tj1; e2 = fv2 + tj2; }
        else    { e0 = e1 = e2 = NEG; }
        float m3 = fmaxf(fmaxf(e0, e1), e2);
        m3 = fmaxf(m3, __shfl_xor(m3, 1, 4));
        m3 = fmaxf(m3, __shfl_xor(m3, 2, 4));
        float s = __expf(e0 - m3) + __expf(e1 - m3) + __expf(e2 - m3);
        s += __shfl_xor(s, 1, 4);
        s += __shfl_xor(s, 2, 4);
        float fvnew = fcur + m3 + __logf(s);
        if (t < 255) fcur = act ? fb[(t + 1) * 12 + i] : 0.0f;
        fv0 = __shfl(fvnew, (j0 + 0) * 4 + q);
        fv1 = __shfl(fvnew, (j0 + 1) * 4 + q);
        fv2 = __shfl(fvnew, (j0 + 2) * 4 + q);
    }

    float e0 = fv0 + trans[12 + j0 + 0];
    float e1 = fv1 + trans[12 + j0 + 1];
    float e2 = fv2 + trans[12 + j0 + 2];
    float m3 = fmaxf(fmaxf(e0, e1), e2);
    m3 = fmaxf(m3, __shfl_xor(m3, 1, 4));
    m3 = fmaxf(m3, __shfl_xor(m3, 2, 4));
    float s = __expf(e0 - m3) + __expf(e1 - m3) + __expf(e2 - m3);
    s += __shfl_xor(s, 1, 4);
    s += __shfl_xor(s, 2, 4);
    float logZ = m3 + __logf(s);

    const int* tg = tags + b * 256;
    float g = 0.0f;
    for (int t = l; t < 256; t += 64){
        int cur = tg[t];
        int prev = t ? tg[t - 1] : 0;
        g += fb[t * 12 + cur] + trans[cur * 12 + prev];
    }
    #pragma unroll
    for (int off = 32; off; off >>= 1) g += __shfl_xor(g, off, 64);
    if (l == 0) scores[b] = logZ - (g + trans[12 + tg[255]]);
}

// ---------- K5: final reduce over batches ----------
__global__ void k5_final(const float* __restrict__ scores, float* __restrict__ out){
    int t = threadIdx.x;
    float v = scores[t];
    #pragma unroll
    for (int off = 16; off; off >>= 1) v += __shfl_xor(v, off, 32);
    if (t == 0) out[0] = v;
}

// ---------- launch ----------
extern "C" void kernel_launch(void* const* d_in, const int* in_sizes, int n_in,
                              void* d_out, int out_size, void* d_ws, size_t ws_size,
                              hipStream_t stream){
    const int*   sent  = (const int*)d_in[0];
    const int*   tags  = (const int*)d_in[1];
    const float* emb   = (const float*)d_in[3];
    const float* Wih_f = (const float*)d_in[4];
    const float* Whh_f = (const float*)d_in[5];
    const float* bih_f = (const float*)d_in[6];
    const float* bhh_f = (const float*)d_in[7];
    const float* Wih_b = (const float*)d_in[8];
    const float* Whh_b = (const float*)d_in[9];
    const float* bih_b = (const float*)d_in[10];
    const float* bhh_b = (const float*)d_in[11];
    const float* Wout  = (const float*)d_in[12];
    const float* bout  = (const float*)d_in[13];
    const float* trans = (const float*)d_in[14];
    const float* h0    = (const float*)d_in[15];
    const float* c0    = (const float*)d_in[16];

    char* ws = (char*)d_ws;
    u16*   X      = (u16*)(ws);                    // 32 MB
    u8*    HS8    = (u8*)(ws + 33554432);          // 4 MB
    float* FEATS  = (float*)(ws + 41943040);       // 384 KB
    u8*    W8     = (u8*)(ws + 42336256);          // 512 KB
    float* SCORES = (float*)(ws + 43384832);       // 128 B
    u8*    W8o    = (u8*)(ws + 43384960);          // 8 KB

    hipLaunchKernelGGL(k0_convert, dim3(512), dim3(256), 0, stream,
                       Whh_f, Whh_b, Wout, (u32*)W8, (u32*)W8o);
    hipLaunchKernelGGL(k1_inproj, dim3(128, 16, 2), dim3(256), 0, stream,
                       sent, emb, Wih_f, bih_f, bhh_f, Wih_b, bih_b, bhh_b, X);
    hipLaunchKernelGGL(k2_lstm, dim3(4), dim3(1024), 0, stream, X, W8, h0, c0, HS8);
    hipLaunchKernelGGL(k3_feats, dim3(128), dim3(256), 0, stream, HS8, W8o, bout, FEATS);
    hipLaunchKernelGGL(k4_crf, dim3(32), dim3(64), 0, stream, FEATS, trans, tags, SCORES);
    hipLaunchKernelGGL(k5_final, dim3(1), dim3(32), 0, stream, SCORES, (float*)d_out);
}

// Round 14
// 450.181 us; speedup vs baseline: 2.2736x; 2.2736x over previous
//
#include <hip/hip_runtime.h>
#include <hip/hip_bf16.h>

typedef unsigned int u32;
typedef unsigned short u16;
typedef unsigned char u8;

typedef __attribute__((ext_vector_type(4))) float f32x4;
typedef __attribute__((ext_vector_type(8))) int i32x8;
typedef __attribute__((ext_vector_type(8))) __bf16 bf16x8;

#define NEG (-10000.0f)
#define WSCALE 16.0f
// i/f/o gates: scaleB = 0x79 (2^-6) = undo WSCALE and apply 0.25 hard-sigmoid slope in HW
// g gate:     scaleB = 0x7B (2^-4) = undo WSCALE

// ---------- helpers ----------
__device__ __forceinline__ float bf2f(u16 x){ return __uint_as_float(((u32)x) << 16); }
__device__ __forceinline__ u16 f2bf(float f){
    u32 u = __float_as_uint(f);
    u32 r = (u + 0x7fffu + ((u >> 16) & 1u)) >> 16;   // RNE
    return (u16)r;
}
__device__ __forceinline__ u32 pk_bf16(float lo, float hi){
    u32 r;
    asm volatile("v_cvt_pk_bf16_f32 %0, %1, %2" : "=v"(r) : "v"(lo), "v"(hi));
    return r;
}
// gate from pre-biased accumulator: single med3
__device__ __forceinline__ float hsig1(float a){
    return __builtin_amdgcn_fmed3f(a, 0.0f, 1.0f);
}
// softsign-rsq tanh: 3 inst
__device__ __forceinline__ float ptanh(float x){
    return x * __builtin_amdgcn_rsqf(__builtin_fmaf(x, x, 1.0f));
}

// ---------- K0: W_hh f32 -> fp8 e4m3 (x16), plus W_out f32 -> fp8 (x64, [16][512]) ----------
__global__ void k0_convert(const float* __restrict__ Whh_f,
                           const float* __restrict__ Whh_b,
                           const float* __restrict__ Wout,
                           u32* __restrict__ w8, u32* __restrict__ w8o){
    int gid = blockIdx.x * blockDim.x + threadIdx.x;   // 4 elems each
    if (gid >= 131072) return;
    int idx = gid * 4;
    int dir = idx >> 18;
    int off = idx & 0x3FFFF;
    const float* W = dir ? Whh_b : Whh_f;
    int pk = __builtin_amdgcn_cvt_pk_fp8_f32(W[off] * WSCALE, W[off + 1] * WSCALE, 0, false);
    pk = __builtin_amdgcn_cvt_pk_fp8_f32(W[off + 2] * WSCALE, W[off + 3] * WSCALE, pk, true);
    w8[gid] = (u32)pk;

    if (gid < 2048){                       // W_out: [16][512] fp8, rows 12..15 = 0
        int i4 = gid * 4;
        int n = i4 >> 9, k = i4 & 511;
        float a = 0, b = 0, c = 0, d = 0;
        if (n < 12){
            const float* wr = Wout + (size_t)n * 512 + k;
            a = wr[0] * 64.0f; b = wr[1] * 64.0f; c = wr[2] * 64.0f; d = wr[3] * 64.0f;
        }
        int p = __builtin_amdgcn_cvt_pk_fp8_f32(a, b, 0, false);
        p = __builtin_amdgcn_cvt_pk_fp8_f32(c, d, p, true);
        w8o[gid] = (u32)p;
    }
}

// ---------- K1: input projection GEMM via bf16 MFMA ----------
// X layout (batch-major): X[dir][m=b*256+t][hp*8 + gate*2 + par], hid = hp*2+par.
// i/f/o gates stored PRE-TRANSFORMED x' = 0.25x + 0.5; g gate raw.
__global__ __launch_bounds__(256) void k1_inproj(
    const int* __restrict__ sent, const float* __restrict__ emb,
    const float* __restrict__ Wih_f, const float* __restrict__ bih_f, const float* __restrict__ bhh_f,
    const float* __restrict__ Wih_b, const float* __restrict__ bih_b, const float* __restrict__ bhh_b,
    u16* __restrict__ X){
    int dir = blockIdx.z;
    const float* W  = dir ? Wih_b : Wih_f;
    const float* b1 = dir ? bih_b : bih_f;
    const float* b2 = dir ? bhh_b : bhh_f;
    u16* Xo = X + (size_t)dir * 8388608;

    __shared__ __align__(16) u16 As[64 * 256];
    __shared__ __align__(16) u16 Bs[64 * 256];

    int tid = threadIdx.x;
    int m0 = blockIdx.x * 64, n0 = blockIdx.y * 64;

    {
        int r = tid >> 2, q = tid & 3;
        int sid = sent[m0 + r];
        const float* arow = emb + (size_t)sid * 256 + q * 64;
        const float* brow = W + (size_t)(n0 + r) * 256 + q * 64;
        #pragma unroll
        for (int g = 0; g < 8; g++){
            int col8 = q * 8 + g;
            int sc = col8 ^ (r & 7);
            float4 a0 = *(const float4*)(arow + g * 8);
            float4 a1 = *(const float4*)(arow + g * 8 + 4);
            u32 pa[4] = { pk_bf16(a0.x, a0.y), pk_bf16(a0.z, a0.w),
                          pk_bf16(a1.x, a1.y), pk_bf16(a1.z, a1.w) };
            *(uint4*)&As[r * 256 + sc * 8] = *(uint4*)pa;
            float4 v0 = *(const float4*)(brow + g * 8);
            float4 v1 = *(const float4*)(brow + g * 8 + 4);
            u32 pb[4] = { pk_bf16(v0.x, v0.y), pk_bf16(v0.z, v0.w),
                          pk_bf16(v1.x, v1.y), pk_bf16(v1.z, v1.w) };
            *(uint4*)&Bs[r * 256 + sc * 8] = *(uint4*)pb;
        }
    }
    __syncthreads();

    int w = tid >> 6, l = tid & 63, lr = l & 15, lk = l >> 4;

    f32x4 acc[4];
    #pragma unroll
    for (int nt = 0; nt < 4; nt++) acc[nt] = (f32x4){0.f, 0.f, 0.f, 0.f};

    int am = w * 16 + lr;
    #pragma unroll
    for (int ko = 0; ko < 8; ko++){
        bf16x8 a = *(const bf16x8*)&As[am * 256 + ((ko * 4 + lk) ^ (am & 7)) * 8];
        #pragma unroll
        for (int nt = 0; nt < 4; nt++){
            int bn = nt * 16 + lr;
            bf16x8 bb = *(const bf16x8*)&Bs[bn * 256 + ((ko * 4 + lk) ^ (bn & 7)) * 8];
            acc[nt] = __builtin_amdgcn_mfma_f32_16x16x32_bf16(a, bb, acc[nt], 0, 0, 0);
        }
    }

    #pragma unroll
    for (int nt = 0; nt < 4; nt++){
        int n = n0 + nt * 16 + lr;
        float bias = b1[n] + b2[n];
        int gate = n >> 8, hid = n & 255;
        int pos = (hid >> 1) * 8 + gate * 2 + (hid & 1);
        bool sig = (gate != 2);
        #pragma unroll
        for (int reg = 0; reg < 4; reg++){
            int m = m0 + w * 16 + lk * 4 + reg;
            float v = acc[nt][reg] + bias;
            if (sig) v = __builtin_fmaf(0.25f, v, 0.5f);
            Xo[(size_t)m * 1024 + pos] = f2bf(v);
        }
    }
}

// ---------- K2: MX-fp8 MFMA LSTM; interleaved MFMA/VALU schedule (no setprio fence) ----------
#define GSCALE(g2) ((g2) == 2 ? 0x7B7B7B7B : 0x79797979)

#define K2_STEP(S, XC, XN)                                                        \
{                                                                                 \
    int tt = dir ? (255 - (S)) : (S);                                             \
    int cur = (S) & 1, nxt = cur ^ 1;                                             \
    int sn = ((S) + 1 < 256) ? (S) + 1 : (S);                                     \
    int tn = dir ? (255 - sn) : sn;                                               \
    const u8* xband = xbase + (u32)(tn * 2048);                                   \
    _Pragma("unroll")                                                             \
    for (int r2 = 0; r2 < 4; r2++)                                                \
        XN[r2] = *(const uint4*)(xband + xo[r2]);                                 \
    i32x8 af0 = *(const i32x8*)&hl[cur][lr][lk * 32];                             \
    i32x8 af1 = *(const i32x8*)&hl[cur][lr][128 + lk * 32];                       \
    f32x4 acc0[4], acc1[4];                                                       \
    _Pragma("unroll")                                                             \
    for (int g2 = 0; g2 < 4; g2++){                                               \
        u32 w0 = ((const u32*)&XC[0])[g2];                                        \
        u32 w1 = ((const u32*)&XC[1])[g2];                                        \
        u32 w2 = ((const u32*)&XC[2])[g2];                                        \
        u32 w3 = ((const u32*)&XC[3])[g2];                                        \
        acc0[g2] = (f32x4){ __uint_as_float(w0 << 16),                            \
                            __uint_as_float(w1 << 16),                            \
                            __uint_as_float(w2 << 16),                            \
                            __uint_as_float(w3 << 16) };                          \
        acc1[g2] = (f32x4){ __uint_as_float(w0 & 0xFFFF0000u),                    \
                            __uint_as_float(w1 & 0xFFFF0000u),                    \
                            __uint_as_float(w2 & 0xFFFF0000u),                    \
                            __uint_as_float(w3 & 0xFFFF0000u) };                  \
    }                                                                             \
    _Pragma("unroll")                                                             \
    for (int g2 = 0; g2 < 4; g2++){                                               \
        acc0[g2] = __builtin_amdgcn_mfma_scale_f32_16x16x128_f8f6f4(              \
            af0, wf[g2][0][0], acc0[g2], 0, 0, 0, 0x7F7F7F7F, 0, GSCALE(g2));     \
        acc0[g2] = __builtin_amdgcn_mfma_scale_f32_16x16x128_f8f6f4(              \
            af1, wf[g2][0][1], acc0[g2], 0, 0, 0, 0x7F7F7F7F, 0, GSCALE(g2));     \
    }                                                                             \
    _Pragma("unroll")                                                             \
    for (int g2 = 0; g2 < 4; g2++){                                               \
        acc1[g2] = __builtin_amdgcn_mfma_scale_f32_16x16x128_f8f6f4(              \
            af0, wf[g2][1][0], acc1[g2], 0, 0, 0, 0x7F7F7F7F, 0, GSCALE(g2));     \
        acc1[g2] = __builtin_amdgcn_mfma_scale_f32_16x16x128_f8f6f4(              \
            af1, wf[g2][1][1], acc1[g2], 0, 0, 0, 0x7F7F7F7F, 0, GSCALE(g2));     \
    }                                                                             \
    float hh0v[4];                                                                \
    _Pragma("unroll")                                                             \
    for (int r2 = 0; r2 < 4; r2++){                                               \
        float gi = hsig1(acc0[0][r2]);                                            \
        float gf = hsig1(acc0[1][r2]);                                            \
        float gg = ptanh(acc0[2][r2]);                                            \
        float go = hsig1(acc0[3][r2]);                                            \
        cst[0][r2] = gf * cst[0][r2] + gi * gg;                                   \
        hh0v[r2] = go * ptanh(cst[0][r2]);                                        \
    }                                                                             \
    u8* hband = hbase + (u32)(tt * 256);                                          \
    _Pragma("unroll")                                                             \
    for (int r2 = 0; r2 < 4; r2++){                                               \
        float gi = hsig1(acc1[0][r2]);                                            \
        float gf = hsig1(acc1[1][r2]);                                            \
        float gg = ptanh(acc1[2][r2]);                                            \
        float go = hsig1(acc1[3][r2]);                                            \
        cst[1][r2] = gf * cst[1][r2] + gi * gg;                                   \
        float hh1 = go * ptanh(cst[1][r2]);                                       \
        int pk = __builtin_amdgcn_cvt_pk_fp8_f32(hh0v[r2], hh1, 0, false);        \
        *(u16*)&hl[nxt][lk * 4 + r2][hid0] = (u16)pk;                             \
        *(u16*)(hband + ho[r2]) = (u16)pk;                                        \
    }                                                                             \
    /* desired emission: 32 init VALU, 8 acc0-MFMA, then 1 MFMA : 12 VALU x8 */   \
    __builtin_amdgcn_sched_group_barrier(0x2, 32, 0);                             \
    __builtin_amdgcn_sched_group_barrier(0x8, 8, 0);                              \
    __builtin_amdgcn_sched_group_barrier(0x8, 1, 0);                              \
    __builtin_amdgcn_sched_group_barrier(0x2, 12, 0);                             \
    __builtin_amdgcn_sched_group_barrier(0x8, 1, 0);                              \
    __builtin_amdgcn_sched_group_barrier(0x2, 12, 0);                             \
    __builtin_amdgcn_sched_group_barrier(0x8, 1, 0);                              \
    __builtin_amdgcn_sched_group_barrier(0x2, 12, 0);                             \
    __builtin_amdgcn_sched_group_barrier(0x8, 1, 0);                              \
    __builtin_amdgcn_sched_group_barrier(0x2, 12, 0);                             \
    __builtin_amdgcn_sched_group_barrier(0x8, 1, 0);                              \
    __builtin_amdgcn_sched_group_barrier(0x2, 12, 0);                             \
    __builtin_amdgcn_sched_group_barrier(0x8, 1, 0);                              \
    __builtin_amdgcn_sched_group_barrier(0x2, 12, 0);                             \
    __builtin_amdgcn_sched_group_barrier(0x8, 1, 0);                              \
    __builtin_amdgcn_sched_group_barrier(0x2, 12, 0);                             \
    __builtin_amdgcn_sched_group_barrier(0x8, 1, 0);                              \
    __builtin_amdgcn_sched_group_barrier(0x2, 12, 0);                             \
    asm volatile("s_waitcnt lgkmcnt(0)" ::: "memory");                            \
    __builtin_amdgcn_s_barrier();                                                 \
    __builtin_amdgcn_sched_barrier(0);                                            \
}

__global__ __launch_bounds__(512) void k2_lstm(
    const u16* __restrict__ X, const u8* __restrict__ w8,
    const float* __restrict__ h0, const float* __restrict__ c0,
    u8* __restrict__ HS8){

    int wg = blockIdx.x;
    int dir = wg >> 1, half = wg & 1;
    int tid = threadIdx.x;
    int w = tid >> 6, l = tid & 63;
    int lr = l & 15, lk = l >> 4;
    int bbase = half * 16;

    __shared__ __align__(16) u8 hl[2][16][272];

    const u8* Wd = w8 + (size_t)dir * 262144;

    int hid0 = w * 32 + 2 * lr;
    int hp = w * 16 + lr;

    // --- weight fragments (loop-invariant, 128 regs) ---
    i32x8 wf[4][2][2];
    #pragma unroll
    for (int g = 0; g < 4; g++)
        #pragma unroll
        for (int t = 0; t < 2; t++)
            #pragma unroll
            for (int ko = 0; ko < 2; ko++)
                wf[g][t][ko] = *(const i32x8*)(Wd + (size_t)(g * 256 + hid0 + t) * 256
                                               + ko * 128 + lk * 32);

    // --- c state ---
    float cst[2][4];
    #pragma unroll
    for (int t = 0; t < 2; t++)
        #pragma unroll
        for (int r = 0; r < 4; r++)
            cst[t][r] = c0[(size_t)(dir * 32 + bbase + lk * 4 + r) * 256 + hid0 + t];

    // --- uniform bases (SGPR) + loop-invariant lane byte offsets (VGPR) ---
    const u8* xbase = (const u8*)(X + (size_t)dir * 8388608);
    u8* hbase = HS8 + (size_t)dir * 2097152;
    u32 xo[4], ho[4];
    #pragma unroll
    for (int r = 0; r < 4; r++){
        xo[r] = (u32)((bbase + lk * 4 + r) * 524288 + hp * 16);
        ho[r] = (u32)((bbase + lk * 4 + r) * 65536 + hid0);
    }

    // --- stage h0 (f32 -> fp8) into hl[0] ---
    {
        int row = tid >> 5;
        int col = (tid & 31) * 8;
        const float* src = h0 + (size_t)(dir * 32 + bbase + row) * 256 + col;
        int p0 = __builtin_amdgcn_cvt_pk_fp8_f32(src[0], src[1], 0, false);
        p0 = __builtin_amdgcn_cvt_pk_fp8_f32(src[2], src[3], p0, true);
        int p1 = __builtin_amdgcn_cvt_pk_fp8_f32(src[4], src[5], 0, false);
        p1 = __builtin_amdgcn_cvt_pk_fp8_f32(src[6], src[7], p1, true);
        u32* dst = (u32*)&hl[0][row][col];
        dst[0] = (u32)p0; dst[1] = (u32)p1;
    }
    __syncthreads();

    // --- prologue: X for s=0 ---
    uint4 xpA[4], xpB[4];
    {
        int tt0 = dir ? 255 : 0;
        const u8* xband = xbase + (u32)(tt0 * 2048);
        #pragma unroll
        for (int r = 0; r < 4; r++)
            xpA[r] = *(const uint4*)(xband + xo[r]);
    }

    for (int s2 = 0; s2 < 256; s2 += 2){
        K2_STEP(s2,     xpA, xpB);
        K2_STEP(s2 + 1, xpB, xpA);
    }
}

// ---------- K3: feats via fp8 MFMA: rows=(b,t), N=16 (12 used), K=512 ----------
__global__ __launch_bounds__(256) void k3_feats(
    const u8* __restrict__ HS8, const u8* __restrict__ W8o,
    const float* __restrict__ bout, float* __restrict__ feats){
    int tid = threadIdx.x;
    int wv = tid >> 6, l = tid & 63, lr = l & 15, lk = l >> 4;
    int tile = blockIdx.x * 4 + wv;          // 0..511
    int b = tile >> 4, t0 = (tile & 15) * 16;

    const u8* hf = HS8 + (size_t)b * 65536 + (t0 + lr) * 256;
    const u8* hb = HS8 + (size_t)(32 + b) * 65536 + (t0 + lr) * 256;
    const u8* wo = W8o + lr * 512;

    f32x4 acc = (f32x4){0.f, 0.f, 0.f, 0.f};
    #pragma unroll
    for (int ko = 0; ko < 8; ko++){
        long a = *(const long*)(hf + ko * 32 + lk * 8);
        long bb = *(const long*)(wo + ko * 32 + lk * 8);
        acc = __builtin_amdgcn_mfma_f32_16x16x32_fp8_fp8(a, bb, acc, 0, 0, 0);
    }
    #pragma unroll
    for (int ko = 0; ko < 8; ko++){
        long a = *(const long*)(hb + ko * 32 + lk * 8);
        long bb = *(const long*)(wo + 256 + ko * 32 + lk * 8);
        acc = __builtin_amdgcn_mfma_f32_16x16x32_fp8_fp8(a, bb, acc, 0, 0, 0);
    }

    if (lr < 12){
        float bias = bout[lr];
        #pragma unroll
        for (int reg = 0; reg < 4; reg++){
            int t = t0 + lk * 4 + reg;
            feats[((size_t)b * 256 + t) * 12 + lr] = acc[reg] * 0.015625f + bias;
        }
    }
}

// ---------- K4: CRF forward + gold, ONE WAVE per batch, barrier-free ----------
__global__ __launch_bounds__(64) void k4_crf(
    const float* __restrict__ feats, const float* __restrict__ trans,
    const int* __restrict__ tags, float* __restrict__ scores){
    int b = blockIdx.x;
    int l = threadIdx.x;
    int i = l >> 2, q = l & 3;
    bool act = (i < 12);
    int j0 = q * 3;
    float tj0 = act ? trans[i * 12 + j0 + 0] : NEG;
    float tj1 = act ? trans[i * 12 + j0 + 1] : NEG;
    float tj2 = act ? trans[i * 12 + j0 + 2] : NEG;
    float fv0 = (j0 == 0) ? 0.0f : NEG;     // START = tag 0
    float fv1 = NEG, fv2 = NEG;
    const float* fb = feats + (size_t)b * 3072;
    float fcur = act ? fb[i] : 0.0f;

    for (int t = 0; t < 256; t++){
        float e0, e1, e2;
        if (act){ e0 = fv0 + tj0; e1 = fv1 + tj1; e2 = fv2 + tj2; }
        else    { e0 = e1 = e2 = NEG; }
        float m3 = fmaxf(fmaxf(e0, e1), e2);
        m3 = fmaxf(m3, __shfl_xor(m3, 1, 4));
        m3 = fmaxf(m3, __shfl_xor(m3, 2, 4));
        float s = __expf(e0 - m3) + __expf(e1 - m3) + __expf(e2 - m3);
        s += __shfl_xor(s, 1, 4);
        s += __shfl_xor(s, 2, 4);
        float fvnew = fcur + m3 + __logf(s);
        if (t < 255) fcur = act ? fb[(t + 1) * 12 + i] : 0.0f;
        fv0 = __shfl(fvnew, (j0 + 0) * 4 + q);
        fv1 = __shfl(fvnew, (j0 + 1) * 4 + q);
        fv2 = __shfl(fvnew, (j0 + 2) * 4 + q);
    }

    float e0 = fv0 + trans[12 + j0 + 0];
    float e1 = fv1 + trans[12 + j0 + 1];
    float e2 = fv2 + trans[12 + j0 + 2];
    float m3 = fmaxf(fmaxf(e0, e1), e2);
    m3 = fmaxf(m3, __shfl_xor(m3, 1, 4));
    m3 = fmaxf(m3, __shfl_xor(m3, 2, 4));
    float s = __expf(e0 - m3) + __expf(e1 - m3) + __expf(e2 - m3);
    s += __shfl_xor(s, 1, 4);
    s += __shfl_xor(s, 2, 4);
    float logZ = m3 + __logf(s);

    const int* tg = tags + b * 256;
    float g = 0.0f;
    for (int t = l; t < 256; t += 64){
        int cur = tg[t];
        int prev = t ? tg[t - 1] : 0;
        g += fb[t * 12 + cur] + trans[cur * 12 + prev];
    }
    #pragma unroll
    for (int off = 32; off; off >>= 1) g += __shfl_xor(g, off, 64);
    if (l == 0) scores[b] = logZ - (g + trans[12 + tg[255]]);
}

// ---------- K5: final reduce over batches ----------
__global__ void k5_final(const float* __restrict__ scores, float* __restrict__ out){
    int t = threadIdx.x;
    float v = scores[t];
    #pragma unroll
    for (int off = 16; off; off >>= 1) v += __shfl_xor(v, off, 32);
    if (t == 0) out[0] = v;
}

// ---------- launch ----------
extern "C" void kernel_launch(void* const* d_in, const int* in_sizes, int n_in,
                              void* d_out, int out_size, void* d_ws, size_t ws_size,
                              hipStream_t stream){
    const int*   sent  = (const int*)d_in[0];
    const int*   tags  = (const int*)d_in[1];
    const float* emb   = (const float*)d_in[3];
    const float* Wih_f = (const float*)d_in[4];
    const float* Whh_f = (const float*)d_in[5];
    const float* bih_f = (const float*)d_in[6];
    const float* bhh_f = (const float*)d_in[7];
    const float* Wih_b = (const float*)d_in[8];
    const float* Whh_b = (const float*)d_in[9];
    const float* bih_b = (const float*)d_in[10];
    const float* bhh_b = (const float*)d_in[11];
    const float* Wout  = (const float*)d_in[12];
    const float* bout  = (const float*)d_in[13];
    const float* trans = (const float*)d_in[14];
    const float* h0    = (const float*)d_in[15];
    const float* c0    = (const float*)d_in[16];

    char* ws = (char*)d_ws;
    u16*   X      = (u16*)(ws);                    // 32 MB
    u8*    HS8    = (u8*)(ws + 33554432);          // 4 MB
    float* FEATS  = (float*)(ws + 41943040);       // 384 KB
    u8*    W8     = (u8*)(ws + 42336256);          // 512 KB
    float* SCORES = (float*)(ws + 43384832);       // 128 B
    u8*    W8o    = (u8*)(ws + 43384960);          // 8 KB

    hipLaunchKernelGGL(k0_convert, dim3(512), dim3(256), 0, stream,
                       Whh_f, Whh_b, Wout, (u32*)W8, (u32*)W8o);
    hipLaunchKernelGGL(k1_inproj, dim3(128, 16, 2), dim3(256), 0, stream,
                       sent, emb, Wih_f, bih_f, bhh_f, Wih_b, bih_b, bhh_b, X);
    hipLaunchKernelGGL(k2_lstm, dim3(4), dim3(512), 0, stream, X, W8, h0, c0, HS8);
    hipLaunchKernelGGL(k3_feats, dim3(128), dim3(256), 0, stream, HS8, W8o, bout, FEATS);
    hipLaunchKernelGGL(k4_crf, dim3(32), dim3(64), 0, stream, FEATS, trans, tags, SCORES);
    hipLaunchKernelGGL(k5_final, dim3(1), dim3(32), 0, stream, SCORES, (float*)d_out);
}

// Round 15
// 411.771 us; speedup vs baseline: 2.4856x; 1.0933x over previous
//
#include <hip/hip_runtime.h>
#include <hip/hip_bf16.h>

typedef unsigned int u32;
typedef unsigned short u16;
typedef unsigned char u8;

typedef __attribute__((ext_vector_type(4))) float f32x4;
typedef __attribute__((ext_vector_type(8))) int i32x8;
typedef __attribute__((ext_vector_type(8))) __bf16 bf16x8;

#define NEG (-10000.0f)
#define WSCALE 16.0f
// i/f/o gates: scaleB = 0x79 (2^-6) = undo WSCALE and apply 0.25 hard-sigmoid slope in HW
// g gate:     scaleB = 0x7B (2^-4) = undo WSCALE

// ---------- helpers ----------
__device__ __forceinline__ float bf2f(u16 x){ return __uint_as_float(((u32)x) << 16); }
__device__ __forceinline__ u16 f2bf(float f){
    u32 u = __float_as_uint(f);
    u32 r = (u + 0x7fffu + ((u >> 16) & 1u)) >> 16;   // RNE
    return (u16)r;
}
__device__ __forceinline__ u32 pk_bf16(float lo, float hi){
    u32 r;
    asm volatile("v_cvt_pk_bf16_f32 %0, %1, %2" : "=v"(r) : "v"(lo), "v"(hi));
    return r;
}
// gate from pre-biased accumulator: single med3
__device__ __forceinline__ float hsig1(float a){
    return __builtin_amdgcn_fmed3f(a, 0.0f, 1.0f);
}
// softsign-rsq tanh: 3 inst
__device__ __forceinline__ float ptanh(float x){
    return x * __builtin_amdgcn_rsqf(__builtin_fmaf(x, x, 1.0f));
}

// ---------- K0: W_hh f32 -> fp8 e4m3 (x16), W_out f32 -> fp8 (x64), zero d_out ----------
__global__ void k0_convert(const float* __restrict__ Whh_f,
                           const float* __restrict__ Whh_b,
                           const float* __restrict__ Wout,
                           u32* __restrict__ w8, u32* __restrict__ w8o,
                           float* __restrict__ out){
    int gid = blockIdx.x * blockDim.x + threadIdx.x;   // 4 elems each
    if (gid == 0) out[0] = 0.0f;                       // accumulator for fused k4
    if (gid >= 131072) return;
    int idx = gid * 4;
    int dir = idx >> 18;
    int off = idx & 0x3FFFF;
    const float* W = dir ? Whh_b : Whh_f;
    int pk = __builtin_amdgcn_cvt_pk_fp8_f32(W[off] * WSCALE, W[off + 1] * WSCALE, 0, false);
    pk = __builtin_amdgcn_cvt_pk_fp8_f32(W[off + 2] * WSCALE, W[off + 3] * WSCALE, pk, true);
    w8[gid] = (u32)pk;

    if (gid < 2048){                       // W_out: [16][512] fp8, rows 12..15 = 0
        int i4 = gid * 4;
        int n = i4 >> 9, k = i4 & 511;
        float a = 0, b = 0, c = 0, d = 0;
        if (n < 12){
            const float* wr = Wout + (size_t)n * 512 + k;
            a = wr[0] * 64.0f; b = wr[1] * 64.0f; c = wr[2] * 64.0f; d = wr[3] * 64.0f;
        }
        int p = __builtin_amdgcn_cvt_pk_fp8_f32(a, b, 0, false);
        p = __builtin_amdgcn_cvt_pk_fp8_f32(c, d, p, true);
        w8o[gid] = (u32)p;
    }
}

// ---------- K1: input projection GEMM via bf16 MFMA, A staged ONCE per block ----------
// grid (128 m-blocks, 2 n-halves, 2 dirs). Each block: stage A (64 tokens) once,
// loop 8 B-panels of 64 gate-rows (B is L2-resident).
// X layout (batch-major): X[dir][m=b*256+t][hp*8 + gate*2 + par], hid = hp*2+par.
// i/f/o gates stored PRE-TRANSFORMED x' = 0.25x + 0.5; g gate raw.
__global__ __launch_bounds__(256) void k1_inproj(
    const int* __restrict__ sent, const float* __restrict__ emb,
    const float* __restrict__ Wih_f, const float* __restrict__ bih_f, const float* __restrict__ bhh_f,
    const float* __restrict__ Wih_b, const float* __restrict__ bih_b, const float* __restrict__ bhh_b,
    u16* __restrict__ X){
    int dir = blockIdx.z;
    const float* W  = dir ? Wih_b : Wih_f;
    const float* b1 = dir ? bih_b : bih_f;
    const float* b2 = dir ? bhh_b : bhh_f;
    u16* Xo = X + (size_t)dir * 8388608;

    __shared__ __align__(16) u16 As[64 * 256];
    __shared__ __align__(16) u16 Bs[64 * 256];

    int tid = threadIdx.x;
    int m0 = blockIdx.x * 64;
    int ntbase = blockIdx.y * 8;           // 8 n-tiles of 64 gate-rows each

    int sr = tid >> 2, sq = tid & 3;       // staging role: row, quarter

    // --- stage A once (visible after first in-loop barrier) ---
    {
        int sid = sent[m0 + sr];
        const float* arow = emb + (size_t)sid * 256 + sq * 64;
        #pragma unroll
        for (int g = 0; g < 8; g++){
            int col8 = sq * 8 + g;
            int sc = col8 ^ (sr & 7);
            float4 a0 = *(const float4*)(arow + g * 8);
            float4 a1 = *(const float4*)(arow + g * 8 + 4);
            u32 pa[4] = { pk_bf16(a0.x, a0.y), pk_bf16(a0.z, a0.w),
                          pk_bf16(a1.x, a1.y), pk_bf16(a1.z, a1.w) };
            *(uint4*)&As[sr * 256 + sc * 8] = *(uint4*)pa;
        }
    }

    int w = tid >> 6, l = tid & 63, lr = l & 15, lk = l >> 4;
    int am = w * 16 + lr;

    for (int nb = 0; nb < 8; nb++){
        int n0 = (ntbase + nb) * 64;

        __syncthreads();                   // prior-iter Bs readers done
        {
            const float* brow = W + (size_t)(n0 + sr) * 256 + sq * 64;
            #pragma unroll
            for (int g = 0; g < 8; g++){
                int col8 = sq * 8 + g;
                int sc = col8 ^ (sr & 7);
                float4 v0 = *(const float4*)(brow + g * 8);
                float4 v1 = *(const float4*)(brow + g * 8 + 4);
                u32 pb[4] = { pk_bf16(v0.x, v0.y), pk_bf16(v0.z, v0.w),
                              pk_bf16(v1.x, v1.y), pk_bf16(v1.z, v1.w) };
                *(uint4*)&Bs[sr * 256 + sc * 8] = *(uint4*)pb;
            }
        }
        __syncthreads();                   // A (iter 0) + B visible

        f32x4 acc[4];
        #pragma unroll
        for (int nt = 0; nt < 4; nt++) acc[nt] = (f32x4){0.f, 0.f, 0.f, 0.f};

        #pragma unroll
        for (int ko = 0; ko < 8; ko++){
            bf16x8 a = *(const bf16x8*)&As[am * 256 + ((ko * 4 + lk) ^ (am & 7)) * 8];
            #pragma unroll
            for (int nt = 0; nt < 4; nt++){
                int bn = nt * 16 + lr;
                bf16x8 bb = *(const bf16x8*)&Bs[bn * 256 + ((ko * 4 + lk) ^ (bn & 7)) * 8];
                acc[nt] = __builtin_amdgcn_mfma_f32_16x16x32_bf16(a, bb, acc[nt], 0, 0, 0);
            }
        }

        #pragma unroll
        for (int nt = 0; nt < 4; nt++){
            int n = n0 + nt * 16 + lr;
            float bias = b1[n] + b2[n];
            int gate = n >> 8, hid = n & 255;
            int pos = (hid >> 1) * 8 + gate * 2 + (hid & 1);
            bool sig = (gate != 2);
            #pragma unroll
            for (int reg = 0; reg < 4; reg++){
                int m = m0 + w * 16 + lk * 4 + reg;
                float v = acc[nt][reg] + bias;
                if (sig) v = __builtin_fmaf(0.25f, v, 0.5f);
                Xo[(size_t)m * 1024 + pos] = f2bf(v);
            }
        }
    }
}

// ---------- K2: MX-fp8 MFMA LSTM (round-11 structure: C-operand X, per-gate HW scale) ----------
#define GSCALE(g2) ((g2) == 2 ? 0x7B7B7B7B : 0x79797979)

#define K2_STEP(S, XC, XN)                                                        \
{                                                                                 \
    int tt = dir ? (255 - (S)) : (S);                                             \
    int cur = (S) & 1, nxt = cur ^ 1;                                             \
    int sn = ((S) + 1 < 256) ? (S) + 1 : (S);                                     \
    int tn = dir ? (255 - sn) : sn;                                               \
    const u8* xband = xbase + (u32)(tn * 2048);                                   \
    _Pragma("unroll")                                                             \
    for (int r2 = 0; r2 < 4; r2++)                                                \
        XN[r2] = *(const uint4*)(xband + xo[r2]);                                 \
    i32x8 af0 = *(const i32x8*)&hl[cur][lr][lk * 32];                             \
    i32x8 af1 = *(const i32x8*)&hl[cur][lr][128 + lk * 32];                       \
    f32x4 acc0[4], acc1[4];                                                       \
    _Pragma("unroll")                                                             \
    for (int g2 = 0; g2 < 4; g2++){                                               \
        u32 w0 = ((const u32*)&XC[0])[g2];                                        \
        u32 w1 = ((const u32*)&XC[1])[g2];                                        \
        u32 w2 = ((const u32*)&XC[2])[g2];                                        \
        u32 w3 = ((const u32*)&XC[3])[g2];                                        \
        acc0[g2] = (f32x4){ __uint_as_float(w0 << 16),                            \
                            __uint_as_float(w1 << 16),                            \
                            __uint_as_float(w2 << 16),                            \
                            __uint_as_float(w3 << 16) };                          \
        acc1[g2] = (f32x4){ __uint_as_float(w0 & 0xFFFF0000u),                    \
                            __uint_as_float(w1 & 0xFFFF0000u),                    \
                            __uint_as_float(w2 & 0xFFFF0000u),                    \
                            __uint_as_float(w3 & 0xFFFF0000u) };                  \
    }                                                                             \
    __builtin_amdgcn_s_setprio(1);                                                \
    _Pragma("unroll")                                                             \
    for (int g2 = 0; g2 < 4; g2++){                                               \
        acc0[g2] = __builtin_amdgcn_mfma_scale_f32_16x16x128_f8f6f4(              \
            af0, wf[g2][0][0], acc0[g2], 0, 0, 0, 0x7F7F7F7F, 0, GSCALE(g2));     \
        acc0[g2] = __builtin_amdgcn_mfma_scale_f32_16x16x128_f8f6f4(              \
            af1, wf[g2][0][1], acc0[g2], 0, 0, 0, 0x7F7F7F7F, 0, GSCALE(g2));     \
    }                                                                             \
    _Pragma("unroll")                                                             \
    for (int g2 = 0; g2 < 4; g2++){                                               \
        acc1[g2] = __builtin_amdgcn_mfma_scale_f32_16x16x128_f8f6f4(              \
            af0, wf[g2][1][0], acc1[g2], 0, 0, 0, 0x7F7F7F7F, 0, GSCALE(g2));     \
        acc1[g2] = __builtin_amdgcn_mfma_scale_f32_16x16x128_f8f6f4(              \
            af1, wf[g2][1][1], acc1[g2], 0, 0, 0, 0x7F7F7F7F, 0, GSCALE(g2));     \
    }                                                                             \
    __builtin_amdgcn_s_setprio(0);                                                \
    float hh0v[4];                                                                \
    _Pragma("unroll")                                                             \
    for (int r2 = 0; r2 < 4; r2++){                                               \
        float gi = hsig1(acc0[0][r2]);                                            \
        float gf = hsig1(acc0[1][r2]);                                            \
        float gg = ptanh(acc0[2][r2]);                                            \
        float go = hsig1(acc0[3][r2]);                                            \
        cst[0][r2] = gf * cst[0][r2] + gi * gg;                                   \
        hh0v[r2] = go * ptanh(cst[0][r2]);                                        \
    }                                                                             \
    u8* hband = hbase + (u32)(tt * 256);                                          \
    _Pragma("unroll")                                                             \
    for (int r2 = 0; r2 < 4; r2++){                                               \
        float gi = hsig1(acc1[0][r2]);                                            \
        float gf = hsig1(acc1[1][r2]);                                            \
        float gg = ptanh(acc1[2][r2]);                                            \
        float go = hsig1(acc1[3][r2]);                                            \
        cst[1][r2] = gf * cst[1][r2] + gi * gg;                                   \
        float hh1 = go * ptanh(cst[1][r2]);                                       \
        int pk = __builtin_amdgcn_cvt_pk_fp8_f32(hh0v[r2], hh1, 0, false);        \
        *(u16*)&hl[nxt][lk * 4 + r2][hid0] = (u16)pk;                             \
        *(u16*)(hband + ho[r2]) = (u16)pk;                                        \
    }                                                                             \
    asm volatile("s_waitcnt lgkmcnt(0)" ::: "memory");                            \
    __builtin_amdgcn_s_barrier();                                                 \
    __builtin_amdgcn_sched_barrier(0);                                            \
}

__global__ __launch_bounds__(512) void k2_lstm(
    const u16* __restrict__ X, const u8* __restrict__ w8,
    const float* __restrict__ h0, const float* __restrict__ c0,
    u8* __restrict__ HS8){

    int wg = blockIdx.x;
    int dir = wg >> 1, half = wg & 1;
    int tid = threadIdx.x;
    int w = tid >> 6, l = tid & 63;
    int lr = l & 15, lk = l >> 4;
    int bbase = half * 16;

    __shared__ __align__(16) u8 hl[2][16][272];

    const u8* Wd = w8 + (size_t)dir * 262144;

    int hid0 = w * 32 + 2 * lr;
    int hp = w * 16 + lr;

    // --- weight fragments (loop-invariant, 128 regs) ---
    i32x8 wf[4][2][2];
    #pragma unroll
    for (int g = 0; g < 4; g++)
        #pragma unroll
        for (int t = 0; t < 2; t++)
            #pragma unroll
            for (int ko = 0; ko < 2; ko++)
                wf[g][t][ko] = *(const i32x8*)(Wd + (size_t)(g * 256 + hid0 + t) * 256
                                               + ko * 128 + lk * 32);

    // --- c state ---
    float cst[2][4];
    #pragma unroll
    for (int t = 0; t < 2; t++)
        #pragma unroll
        for (int r = 0; r < 4; r++)
            cst[t][r] = c0[(size_t)(dir * 32 + bbase + lk * 4 + r) * 256 + hid0 + t];

    // --- uniform bases (SGPR) + loop-invariant lane byte offsets (VGPR) ---
    const u8* xbase = (const u8*)(X + (size_t)dir * 8388608);
    u8* hbase = HS8 + (size_t)dir * 2097152;
    u32 xo[4], ho[4];
    #pragma unroll
    for (int r = 0; r < 4; r++){
        xo[r] = (u32)((bbase + lk * 4 + r) * 524288 + hp * 16);
        ho[r] = (u32)((bbase + lk * 4 + r) * 65536 + hid0);
    }

    // --- stage h0 (f32 -> fp8) into hl[0] ---
    {
        int row = tid >> 5;
        int col = (tid & 31) * 8;
        const float* src = h0 + (size_t)(dir * 32 + bbase + row) * 256 + col;
        int p0 = __builtin_amdgcn_cvt_pk_fp8_f32(src[0], src[1], 0, false);
        p0 = __builtin_amdgcn_cvt_pk_fp8_f32(src[2], src[3], p0, true);
        int p1 = __builtin_amdgcn_cvt_pk_fp8_f32(src[4], src[5], 0, false);
        p1 = __builtin_amdgcn_cvt_pk_fp8_f32(src[6], src[7], p1, true);
        u32* dst = (u32*)&hl[0][row][col];
        dst[0] = (u32)p0; dst[1] = (u32)p1;
    }
    __syncthreads();

    // --- prologue: X for s=0 ---
    uint4 xpA[4], xpB[4];
    {
        int tt0 = dir ? 255 : 0;
        const u8* xband = xbase + (u32)(tt0 * 2048);
        #pragma unroll
        for (int r = 0; r < 4; r++)
            xpA[r] = *(const uint4*)(xband + xo[r]);
    }

    for (int s2 = 0; s2 < 256; s2 += 2){
        K2_STEP(s2,     xpA, xpB);
        K2_STEP(s2 + 1, xpB, xpA);
    }
}

// ---------- K3: feats via fp8 MFMA: rows=(b,t), N=16 (12 used), K=512 ----------
__global__ __launch_bounds__(256) void k3_feats(
    const u8* __restrict__ HS8, const u8* __restrict__ W8o,
    const float* __restrict__ bout, float* __restrict__ feats){
    int tid = threadIdx.x;
    int wv = tid >> 6, l = tid & 63, lr = l & 15, lk = l >> 4;
    int tile = blockIdx.x * 4 + wv;          // 0..511
    int b = tile >> 4, t0 = (tile & 15) * 16;

    const u8* hf = HS8 + (size_t)b * 65536 + (t0 + lr) * 256;
    const u8* hb = HS8 + (size_t)(32 + b) * 65536 + (t0 + lr) * 256;
    const u8* wo = W8o + lr * 512;

    f32x4 acc = (f32x4){0.f, 0.f, 0.f, 0.f};
    #pragma unroll
    for (int ko = 0; ko < 8; ko++){
        long a = *(const long*)(hf + ko * 32 + lk * 8);
        long bb = *(const long*)(wo + ko * 32 + lk * 8);
        acc = __builtin_amdgcn_mfma_f32_16x16x32_fp8_fp8(a, bb, acc, 0, 0, 0);
    }
    #pragma unroll
    for (int ko = 0; ko < 8; ko++){
        long a = *(const long*)(hb + ko * 32 + lk * 8);
        long bb = *(const long*)(wo + 256 + ko * 32 + lk * 8);
        acc = __builtin_amdgcn_mfma_f32_16x16x32_fp8_fp8(a, bb, acc, 0, 0, 0);
    }

    if (lr < 12){
        float bias = bout[lr];
        #pragma unroll
        for (int reg = 0; reg < 4; reg++){
            int t = t0 + lk * 4 + reg;
            feats[((size_t)b * 256 + t) * 12 + lr] = acc[reg] * 0.015625f + bias;
        }
    }
}

// ---------- K4: CRF forward + gold, ONE WAVE per batch; atomicAdd into d_out ----------
__global__ __launch_bounds__(64) void k4_crf(
    const float* __restrict__ feats, const float* __restrict__ trans,
    const int* __restrict__ tags, float* __restrict__ out){
    int b = blockIdx.x;
    int l = threadIdx.x;
    int i = l >> 2, q = l & 3;
    bool act = (i < 12);
    int j0 = q * 3;
    float tj0 = act ? trans[i * 12 + j0 + 0] : NEG;
    float tj1 = act ? trans[i * 12 + j0 + 1] : NEG;
    float tj2 = act ? trans[i * 12 + j0 + 2] : NEG;
    float fv0 = (j0 == 0) ? 0.0f : NEG;     // START = tag 0
    float fv1 = NEG, fv2 = NEG;
    const float* fb = feats + (size_t)b * 3072;
    float fcur = act ? fb[i] : 0.0f;

    for (int t = 0; t < 256; t++){
        float e0, e1, e2;
        if (act){ e0 = fv0 + tj0; e1 = fv1 + tj1; e2 = fv2 + tj2; }
        else    { e0 = e1 = e2 = NEG; }
        float m3 = fmaxf(fmaxf(e0, e1), e2);
        m3 = fmaxf(m3, __shfl_xor(m3, 1, 4));
        m3 = fmaxf(m3, __shfl_xor(m3, 2, 4));
        float s = __expf(e0 - m3) + __expf(e1 - m3) + __expf(e2 - m3);
        s += __shfl_xor(s, 1, 4);
        s += __shfl_xor(s, 2, 4);
        float fvnew = fcur + m3 + __logf(s);
        if (t < 255) fcur = act ? fb[(t + 1) * 12 + i] : 0.0f;
        fv0 = __shfl(fvnew, (j0 + 0) * 4 + q);
        fv1 = __shfl(fvnew, (j0 + 1) * 4 + q);
        fv2 = __shfl(fvnew, (j0 + 2) * 4 + q);
    }

    float e0 = fv0 + trans[12 + j0 + 0];
    float e1 = fv1 + trans[12 + j0 + 1];
    float e2 = fv2 + trans[12 + j0 + 2];
    float m3 = fmaxf(fmaxf(e0, e1), e2);
    m3 = fmaxf(m3, __shfl_xor(m3, 1, 4));
    m3 = fmaxf(m3, __shfl_xor(m3, 2, 4));
    float s = __expf(e0 - m3) + __expf(e1 - m3) + __expf(e2 - m3);
    s += __shfl_xor(s, 1, 4);
    s += __shfl_xor(s, 2, 4);
    float logZ = m3 + __logf(s);

    const int* tg = tags + b * 256;
    float g = 0.0f;
    for (int t = l; t < 256; t += 64){
        int cur = tg[t];
        int prev = t ? tg[t - 1] : 0;
        g += fb[t * 12 + cur] + trans[cur * 12 + prev];
    }
    #pragma unroll
    for (int off = 32; off; off >>= 1) g += __shfl_xor(g, off, 64);
    if (l == 0) atomicAdd(out, logZ - (g + trans[12 + tg[255]]));
}

// ---------- launch ----------
extern "C" void kernel_launch(void* const* d_in, const int* in_sizes, int n_in,
                              void* d_out, int out_size, void* d_ws, size_t ws_size,
                              hipStream_t stream){
    const int*   sent  = (const int*)d_in[0];
    const int*   tags  = (const int*)d_in[1];
    const float* emb   = (const float*)d_in[3];
    const float* Wih_f = (const float*)d_in[4];
    const float* Whh_f = (const float*)d_in[5];
    const float* bih_f = (const float*)d_in[6];
    const float* bhh_f = (const float*)d_in[7];
    const float* Wih_b = (const float*)d_in[8];
    const float* Whh_b = (const float*)d_in[9];
    const float* bih_b = (const float*)d_in[10];
    const float* bhh_b = (const float*)d_in[11];
    const float* Wout  = (const float*)d_in[12];
    const float* bout  = (const float*)d_in[13];
    const float* trans = (const float*)d_in[14];
    const float* h0    = (const float*)d_in[15];
    const float* c0    = (const float*)d_in[16];

    char* ws = (char*)d_ws;
    u16*   X      = (u16*)(ws);                    // 32 MB
    u8*    HS8    = (u8*)(ws + 33554432);          // 4 MB
    float* FEATS  = (float*)(ws + 41943040);       // 384 KB
    u8*    W8     = (u8*)(ws + 42336256);          // 512 KB
    u8*    W8o    = (u8*)(ws + 43384960);          // 8 KB

    hipLaunchKernelGGL(k0_convert, dim3(512), dim3(256), 0, stream,
                       Whh_f, Whh_b, Wout, (u32*)W8, (u32*)W8o, (float*)d_out);
    hipLaunchKernelGGL(k1_inproj, dim3(128, 2, 2), dim3(256), 0, stream,
                       sent, emb, Wih_f, bih_f, bhh_f, Wih_b, bih_b, bhh_b, X);
    hipLaunchKernelGGL(k2_lstm, dim3(4), dim3(512), 0, stream, X, W8, h0, c0, HS8);
    hipLaunchKernelGGL(k3_feats, dim3(128), dim3(256), 0, stream, HS8, W8o, bout, FEATS);
    hipLaunchKernelGGL(k4_crf, dim3(32), dim3(64), 0, stream, FEATS, trans, tags, (float*)d_out);
}